// Round 1
// baseline (232.084 us; speedup 1.0000x reference)
//
#include <hip/hip_runtime.h>

#define S_LEN   2048
#define BATCH   32
#define NF      1024
#define CTX     20
#define KW      21            // CTX + 1 taps
#define T_OUT   128           // output t-steps per block
#define F_TILE  32            // floats of feature dim per block
#define NROWS   (T_OUT + CTX) // 148 input rows staged
#define XSTRIDE 36            // padded row stride (floats); 36*4=144B, 16B aligned
#define R_PER_T 4             // consecutive t outputs per thread

__global__ __launch_bounds__(256)
void lookahead_dwconv_kernel(const float* __restrict__ x,
                             const float* __restrict__ w,
                             float* __restrict__ out) {
    __shared__ float xlds[NROWS * XSTRIDE];
    __shared__ float wlds[KW][F_TILE];

    const int tid    = threadIdx.x;
    const int t_tile = blockIdx.x;
    const int f_tile = blockIdx.y;
    const int b      = blockIdx.z;
    const int t0     = t_tile * T_OUT;
    const int f0     = f_tile * F_TILE;

    // ---- stage weights: w[f0..f0+31][0..20] -> wlds[k][f_local] (transposed) ----
    for (int i = tid; i < F_TILE * KW; i += 256) {
        int fl = i / KW;
        int k  = i - fl * KW;
        wlds[k][fl] = w[(f0 + fl) * KW + k];
    }

    // ---- stage x tile: rows t0..t0+147, 32 floats each, zero-pad past S_LEN ----
    for (int i = tid; i < NROWS * (F_TILE / 4); i += 256) {
        int row = i >> 3;       // 0..147
        int f4  = i & 7;        // 0..7
        int t   = t0 + row;
        float4 v = make_float4(0.f, 0.f, 0.f, 0.f);
        if (t < S_LEN) {
            v = *reinterpret_cast<const float4*>(
                    &x[((size_t)t * BATCH + b) * NF + f0 + f4 * 4]);
        }
        *reinterpret_cast<float4*>(&xlds[row * XSTRIDE + f4 * 4]) = v;
    }
    __syncthreads();

    // ---- per-thread work: fixed f4, 4 consecutive t outputs ----
    const int f4    = tid & 7;         // 0..7
    const int tg    = tid >> 3;        // 0..31
    const int tbase = tg * R_PER_T;    // 0..124

    // weights into registers (broadcast LDS reads: 8 distinct addrs / wave)
    float4 wreg[KW];
    #pragma unroll
    for (int k = 0; k < KW; ++k)
        wreg[k] = *reinterpret_cast<const float4*>(&wlds[k][f4 * 4]);

    float4 acc[R_PER_T];
    #pragma unroll
    for (int r = 0; r < R_PER_T; ++r)
        acc[r] = make_float4(0.f, 0.f, 0.f, 0.f);

    // register sliding window: stream 24 input rows, each feeds up to 4 accs
    #pragma unroll
    for (int s = 0; s < R_PER_T + CTX; ++s) {
        float4 xv = *reinterpret_cast<const float4*>(
                        &xlds[(tbase + s) * XSTRIDE + f4 * 4]);
        #pragma unroll
        for (int r = 0; r < R_PER_T; ++r) {
            int k = s - r;
            if (k >= 0 && k < KW) {
                acc[r].x = fmaf(xv.x, wreg[k].x, acc[r].x);
                acc[r].y = fmaf(xv.y, wreg[k].y, acc[r].y);
                acc[r].z = fmaf(xv.z, wreg[k].z, acc[r].z);
                acc[r].w = fmaf(xv.w, wreg[k].w, acc[r].w);
            }
        }
    }

    // ---- store: coalesced 128B per 8-lane row group ----
    #pragma unroll
    for (int r = 0; r < R_PER_T; ++r) {
        int t = t0 + tbase + r;
        *reinterpret_cast<float4*>(
            &out[((size_t)t * BATCH + b) * NF + f0 + f4 * 4]) = acc[r];
    }
}

extern "C" void kernel_launch(void* const* d_in, const int* in_sizes, int n_in,
                              void* d_out, int out_size, void* d_ws, size_t ws_size,
                              hipStream_t stream) {
    const float* x = (const float*)d_in[0];
    const float* w = (const float*)d_in[1];
    float* out     = (float*)d_out;

    dim3 grid(S_LEN / T_OUT, NF / F_TILE, BATCH);  // (16, 32, 32)
    dim3 block(256);
    lookahead_dwconv_kernel<<<grid, block, 0, stream>>>(x, w, out);
}